// Round 13
// baseline (898.056 us; speedup 1.0000x reference)
//
#include <hip/hip_runtime.h>

#define S_LEN 1024
#define BATCH 4096
#define NIN 64
#define NHID 128
#define BT 32      // batch rows per block = TWO independent 16-row chains

typedef __attribute__((ext_vector_type(8))) short bf16x8;
typedef __attribute__((ext_vector_type(4))) float f32x4;

__device__ __forceinline__ unsigned cvt_pk(float lo, float hi) {
    unsigned r;
    asm("v_cvt_pk_bf16_f32 %0, %1, %2" : "=v"(r) : "v"(lo), "v"(hi));
    return r;
}
__device__ __forceinline__ float tanh_fast(float z) {
    float u = __builtin_amdgcn_exp2f(z * 2.885390081777927f);
    return (u - 1.0f) * __builtin_amdgcn_rcpf(u + 1.0f);
}
// barrier without vmcnt drain (x prefetch loads stay in flight)
__device__ __forceinline__ void lds_barrier() {
    asm volatile("s_waitcnt lgkmcnt(0)\n\ts_barrier" ::: "memory");
    __builtin_amdgcn_sched_barrier(0);
}

#define MFMA __builtin_amdgcn_mfma_f32_16x16x32_bf16

__device__ __forceinline__ bf16x8 pack8(const f32x4& a, const f32x4& b) {
    union { bf16x8 v; unsigned u[4]; } r;
    r.u[0] = cvt_pk(a[0], a[1]); r.u[1] = cvt_pk(a[2], a[3]);
    r.u[2] = cvt_pk(b[0], b[1]); r.u[3] = cvt_pk(b[2], b[3]);
    return r.v;
}

// Permuted-k (verified R6-R9): B-slot (kk,kg,j) carries logical hidden index
// m = 32kk + 16*(j>>2) + 4kg + (j&3). Wave OWN (=wv) owns tt {2*OWN, 2*OWN+1}:
// its accs pack same-lane into B-slot OWN; 3 partner slots cross LDS.
// TWO independent chains (A: rows bb0.., B: rows bb0+16..) interleaved in the
// same instruction stream: chain B's issue fills chain A's dependency stalls.
// LDS per chain: 2 bufs x 4KB (buf at b<<12, slot kk<<10, lane<<4); B at +8KB.

__global__ __launch_bounds__(256, 1)
void rnn_kernel(const float* __restrict__ x,
                const float* __restrict__ W_ih,
                const float* __restrict__ b_ih,
                const float* __restrict__ W_hh,
                const float* __restrict__ b_hh,
                float* __restrict__ out)
{
    __shared__ __align__(16) char lds[16384];
    const int tid  = threadIdx.x;
    const int wv   = tid >> 6;        // 0..3 — one wave per SIMD, uniform code
    const int lane = tid & 63;
    const int col  = lane & 15;
    const int kg   = lane >> 4;
    const int bb0  = blockIdx.x * BT;

    // zero both chains' exchange buffers (h_0 = 0)
    for (int i = tid; i < 4096; i += 256) ((int*)lds)[i] = 0;

    const int OWN = wv;               // runtime-uniform; addresses only
    char* lbxA = lds + (lane << 4);
    char* lbxB = lbxA + 8192;
    char*       wpA  = lbxA + (OWN << 10);
    const char* rpA1 = lbxA + ((((OWN + 1) & 3)) << 10);
    const char* rpA2 = lbxA + ((((OWN + 2) & 3)) << 10);
    const char* rpA3 = lbxA + ((((OWN + 3) & 3)) << 10);
    char*       wpB  = lbxB + (OWN << 10);
    const char* rpB1 = lbxB + ((((OWN + 1) & 3)) << 10);
    const char* rpB2 = lbxB + ((((OWN + 2) & 3)) << 10);
    const char* rpB3 = lbxB + ((((OWN + 3) & 3)) << 10);

    // ---- persistent weights (SHARED by both chains)
    bf16x8 whh0[4], whh1[4];
    const int tt0 = 2 * OWN, tt1 = tt0 + 1;
    #pragma unroll
    for (int q = 0; q < 4; ++q) {
        const int kkq = (OWN + q) & 3;
        {
            const float* pw = W_hh + (16 * tt0 + col) * NHID + 32 * kkq + 4 * kg;
            whh0[q] = pack8(*(const f32x4*)(pw), *(const f32x4*)(pw + 16));
        }
        {
            const float* pw = W_hh + (16 * tt1 + col) * NHID + 32 * kkq + 4 * kg;
            whh1[q] = pack8(*(const f32x4*)(pw), *(const f32x4*)(pw + 16));
        }
    }
    bf16x8 wihA0, wihB0, wihA1, wihB1;
    {
        const float* q0 = W_ih + (16 * tt0 + col) * NIN + 8 * kg;
        const float* q1 = W_ih + (16 * tt1 + col) * NIN + 8 * kg;
        wihA0 = pack8(*(const f32x4*)(q0),      *(const f32x4*)(q0 + 4));
        wihB0 = pack8(*(const f32x4*)(q0 + 32), *(const f32x4*)(q0 + 36));
        wihA1 = pack8(*(const f32x4*)(q1),      *(const f32x4*)(q1 + 4));
        wihB1 = pack8(*(const f32x4*)(q1 + 32), *(const f32x4*)(q1 + 36));
    }
    f32x4 bias0, bias1;
    {
        f32x4 bi = *(const f32x4*)(b_ih + 16 * tt0 + 4 * kg);
        f32x4 bh = *(const f32x4*)(b_hh + 16 * tt0 + 4 * kg);
        bias0 = bi + bh;
        bi = *(const f32x4*)(b_ih + 16 * tt1 + 4 * kg);
        bh = *(const f32x4*)(b_hh + 16 * tt1 + 4 * kg);
        bias1 = bi + bh;
    }

    const float* xlaneA = x + ((size_t)bb0 + col) * NIN + kg * 8;
    const float* xlaneB = x + ((size_t)bb0 + 16 + col) * NIN + kg * 8;

    auto loadStage = [&](const float* xl,
                         f32x4& v0, f32x4& v1, f32x4& v2, f32x4& v3, int t) {
        if (t < S_LEN) {
            const float* p = xl + (size_t)t * (BATCH * NIN);
            v0 = *(const f32x4*)(p);      v1 = *(const f32x4*)(p + 4);
            v2 = *(const f32x4*)(p + 32); v3 = *(const f32x4*)(p + 36);
        }
    };
    auto computeXP = [&](const f32x4& v0, const f32x4& v1,
                         const f32x4& v2, const f32x4& v3,
                         f32x4& o0, f32x4& o1) {
        union { bf16x8 v; unsigned u[4]; } xa, xb;
        xa.u[0] = cvt_pk(v0[0], v0[1]); xa.u[1] = cvt_pk(v0[2], v0[3]);
        xa.u[2] = cvt_pk(v1[0], v1[1]); xa.u[3] = cvt_pk(v1[2], v1[3]);
        xb.u[0] = cvt_pk(v2[0], v2[1]); xb.u[1] = cvt_pk(v2[2], v2[3]);
        xb.u[2] = cvt_pk(v3[0], v3[1]); xb.u[3] = cvt_pk(v3[2], v3[3]);
        f32x4 p0 = bias0, p1 = bias1;
        p0 = MFMA(wihA0, xa.v, p0, 0, 0, 0);
        p1 = MFMA(wihA1, xa.v, p1, 0, 0, 0);
        p0 = MFMA(wihB0, xb.v, p0, 0, 0, 0);
        p1 = MFMA(wihB1, xb.v, p1, 0, 0, 0);
        o0 = p0; o1 = p1;
    };

    // ---- prologue (R9 pattern, per chain)
    f32x4 SA00, SA01, SA02, SA03, SA10, SA11, SA12, SA13;
    f32x4 SA20, SA21, SA22, SA23, SA30, SA31, SA32, SA33;
    f32x4 SB00, SB01, SB02, SB03, SB10, SB11, SB12, SB13;
    f32x4 SB20, SB21, SB22, SB23, SB30, SB31, SB32, SB33;
    loadStage(xlaneA, SA00, SA01, SA02, SA03, 0);
    loadStage(xlaneA, SA10, SA11, SA12, SA13, 1);
    loadStage(xlaneA, SA20, SA21, SA22, SA23, 2);
    loadStage(xlaneA, SA30, SA31, SA32, SA33, 3);
    loadStage(xlaneB, SB00, SB01, SB02, SB03, 0);
    loadStage(xlaneB, SB10, SB11, SB12, SB13, 1);
    loadStage(xlaneB, SB20, SB21, SB22, SB23, 2);
    loadStage(xlaneB, SB30, SB31, SB32, SB33, 3);
    f32x4 xcA0, xcA1, xnA0, xnA1, xcB0, xcB1, xnB0, xnB1;
    computeXP(SA00, SA01, SA02, SA03, xcA0, xcA1);
    loadStage(xlaneA, SA00, SA01, SA02, SA03, 4);
    computeXP(SB00, SB01, SB02, SB03, xcB0, xcB1);
    loadStage(xlaneB, SB00, SB01, SB02, SB03, 4);
    bf16x8 BoA = {0, 0, 0, 0, 0, 0, 0, 0};
    bf16x8 BoB = {0, 0, 0, 0, 0, 0, 0, 0};
    __syncthreads();                            // B-zeros visible

    auto cstep = [&](int t,
                     f32x4& sa0, f32x4& sa1, f32x4& sa2, f32x4& sa3,
                     f32x4& sb0, f32x4& sb1, f32x4& sb2, f32x4& sb3,
                     const f32x4& cA0, const f32x4& cA1, f32x4& nA0, f32x4& nA1,
                     const f32x4& cB0, const f32x4& cB1, f32x4& nB0, f32x4& nB1,
                     bool last) {
        const int rb = (t & 1) << 12;
        // partner reads for both chains issue first
        bf16x8 PA1 = *(const bf16x8*)(rpA1 + rb);
        bf16x8 PA2 = *(const bf16x8*)(rpA2 + rb);
        bf16x8 PA3 = *(const bf16x8*)(rpA3 + rb);
        bf16x8 PB1 = *(const bf16x8*)(rpB1 + rb);
        bf16x8 PB2 = *(const bf16x8*)(rpB2 + rb);
        bf16x8 PB3 = *(const bf16x8*)(rpB3 + rb);

        f32x4 aA0 = cA0, aA1 = cA1, aB0 = cB0, aB1 = cB1;
        aA0 = MFMA(whh0[0], BoA, aA0, 0, 0, 0);   // own slots: no LDS wait
        aA1 = MFMA(whh1[0], BoA, aA1, 0, 0, 0);
        aB0 = MFMA(whh0[0], BoB, aB0, 0, 0, 0);
        aB1 = MFMA(whh1[0], BoB, aB1, 0, 0, 0);

        computeXP(sa0, sa1, sa2, sa3, nA0, nA1);  // xp(t+1), chain A
        loadStage(xlaneA, sa0, sa1, sa2, sa3, t + 5);
        computeXP(sb0, sb1, sb2, sb3, nB0, nB1);  // xp(t+1), chain B
        loadStage(xlaneB, sb0, sb1, sb2, sb3, t + 5);

        // partner MFMAs, A/B interleaved (B fills A's dependency stalls)
        aA0 = MFMA(whh0[1], PA1, aA0, 0, 0, 0);
        aB0 = MFMA(whh0[1], PB1, aB0, 0, 0, 0);
        aA1 = MFMA(whh1[1], PA1, aA1, 0, 0, 0);
        aB1 = MFMA(whh1[1], PB1, aB1, 0, 0, 0);
        aA0 = MFMA(whh0[2], PA2, aA0, 0, 0, 0);
        aB0 = MFMA(whh0[2], PB2, aB0, 0, 0, 0);
        aA1 = MFMA(whh1[2], PA2, aA1, 0, 0, 0);
        aB1 = MFMA(whh1[2], PB2, aB1, 0, 0, 0);
        aA0 = MFMA(whh0[3], PA3, aA0, 0, 0, 0);
        aB0 = MFMA(whh0[3], PB3, aB0, 0, 0, 0);
        aA1 = MFMA(whh1[3], PA3, aA1, 0, 0, 0);
        aB1 = MFMA(whh1[3], PB3, aB1, 0, 0, 0);

        #pragma unroll
        for (int i = 0; i < 4; ++i) aA0[i] = tanh_fast(aA0[i]);
        #pragma unroll
        for (int i = 0; i < 4; ++i) aB0[i] = tanh_fast(aB0[i]);
        #pragma unroll
        for (int i = 0; i < 4; ++i) aA1[i] = tanh_fast(aA1[i]);
        #pragma unroll
        for (int i = 0; i < 4; ++i) aB1[i] = tanh_fast(aB1[i]);

        if (last) {
            float* obA = out + ((size_t)bb0 + col) * NHID + 32 * OWN + 4 * kg;
            float* obB = out + ((size_t)bb0 + 16 + col) * NHID + 32 * OWN + 4 * kg;
            *(f32x4*)(obA)      = aA0;
            *(f32x4*)(obA + 16) = aA1;
            *(f32x4*)(obB)      = aB0;
            *(f32x4*)(obB + 16) = aB1;
            lds_barrier();
            return;
        }
        {
            union { bf16x8 v; unsigned u[4]; } fb;
            fb.u[0] = cvt_pk(aA0[0], aA0[1]); fb.u[1] = cvt_pk(aA0[2], aA0[3]);
            fb.u[2] = cvt_pk(aA1[0], aA1[1]); fb.u[3] = cvt_pk(aA1[2], aA1[3]);
            BoA = fb.v;
            *(bf16x8*)(wpA + (((t + 1) & 1) << 12)) = BoA;
        }
        {
            union { bf16x8 v; unsigned u[4]; } fb;
            fb.u[0] = cvt_pk(aB0[0], aB0[1]); fb.u[1] = cvt_pk(aB0[2], aB0[3]);
            fb.u[2] = cvt_pk(aB1[0], aB1[1]); fb.u[3] = cvt_pk(aB1[2], aB1[3]);
            BoB = fb.v;
            *(bf16x8*)(wpB + (((t + 1) & 1) << 12)) = BoB;
        }
        lds_barrier();
    };

    for (int m = 0; m < 255; ++m) {
        const int t = 4 * m;
        cstep(t + 0, SA10, SA11, SA12, SA13, SB10, SB11, SB12, SB13,
              xcA0, xcA1, xnA0, xnA1, xcB0, xcB1, xnB0, xnB1, false);
        cstep(t + 1, SA20, SA21, SA22, SA23, SB20, SB21, SB22, SB23,
              xnA0, xnA1, xcA0, xcA1, xnB0, xnB1, xcB0, xcB1, false);
        cstep(t + 2, SA30, SA31, SA32, SA33, SB30, SB31, SB32, SB33,
              xcA0, xcA1, xnA0, xnA1, xcB0, xcB1, xnB0, xnB1, false);
        cstep(t + 3, SA00, SA01, SA02, SA03, SB00, SB01, SB02, SB03,
              xnA0, xnA1, xcA0, xcA1, xnB0, xnB1, xcB0, xcB1, false);
    }
    cstep(1020, SA10, SA11, SA12, SA13, SB10, SB11, SB12, SB13,
          xcA0, xcA1, xnA0, xnA1, xcB0, xcB1, xnB0, xnB1, false);
    cstep(1021, SA20, SA21, SA22, SA23, SB20, SB21, SB22, SB23,
          xnA0, xnA1, xcA0, xcA1, xnB0, xnB1, xcB0, xcB1, false);
    cstep(1022, SA30, SA31, SA32, SA33, SB30, SB31, SB32, SB33,
          xcA0, xcA1, xnA0, xnA1, xcB0, xcB1, xnB0, xnB1, false);
    cstep(1023, SA00, SA01, SA02, SA03, SB00, SB01, SB02, SB03,
          xnA0, xnA1, xcA0, xcA1, xnB0, xnB1, xcB0, xcB1, true);
}

extern "C" void kernel_launch(void* const* d_in, const int* in_sizes, int n_in,
                              void* d_out, int out_size, void* d_ws, size_t ws_size,
                              hipStream_t stream) {
    const float* x    = (const float*)d_in[0];
    const float* W_ih = (const float*)d_in[1];
    const float* b_ih = (const float*)d_in[2];
    const float* W_hh = (const float*)d_in[3];
    const float* b_hh = (const float*)d_in[4];
    float* out = (float*)d_out;

    dim3 grid(BATCH / BT);
    dim3 block(256);
    rnn_kernel<<<grid, block, 0, stream>>>(x, W_ih, b_ih, W_hh, b_hh, out);
}

// Round 14
// 457.593 us; speedup vs baseline: 1.9626x; 1.9626x over previous
//
#include <hip/hip_runtime.h>

#define S_LEN 1024
#define BATCH 4096
#define NIN 64
#define NHID 128
#define BT 16      // batch rows per block (one h-chain per block)

typedef __attribute__((ext_vector_type(8))) short bf16x8;
typedef __attribute__((ext_vector_type(4))) float f32x4;

__device__ __forceinline__ unsigned cvt_pk(float lo, float hi) {
    unsigned r;
    asm("v_cvt_pk_bf16_f32 %0, %1, %2" : "=v"(r) : "v"(lo), "v"(hi));
    return r;
}
__device__ __forceinline__ float tanh_fast(float z) {
    float u = __builtin_amdgcn_exp2f(z * 2.885390081777927f);
    return (u - 1.0f) * __builtin_amdgcn_rcpf(u + 1.0f);
}
// barrier without vmcnt drain (x prefetch loads stay in flight)
__device__ __forceinline__ void lds_barrier() {
    asm volatile("s_waitcnt lgkmcnt(0)\n\ts_barrier" ::: "memory");
    __builtin_amdgcn_sched_barrier(0);
}

#define MFMA __builtin_amdgcn_mfma_f32_16x16x32_bf16

__device__ __forceinline__ bf16x8 pack8(const f32x4& a, const f32x4& b) {
    union { bf16x8 v; unsigned u[4]; } r;
    r.u[0] = cvt_pk(a[0], a[1]); r.u[1] = cvt_pk(a[2], a[3]);
    r.u[2] = cvt_pk(b[0], b[1]); r.u[3] = cvt_pk(b[2], b[3]);
    return r.v;
}

// Permuted-k (verified R6-R9): B-slot (kk,kg,j) carries logical hidden index
// m = 32kk + 16*(j>>2) + 4kg + (j&3). Wave OWN (=wv) owns tt {2*OWN, 2*OWN+1}:
// its accs pack same-lane into B-slot OWN; own slot stays in registers, 3
// partner slots cross LDS. LDS: 2 bufs x 4KB (buf b<<12, slot kk<<10, lane<<4).
// R14 change vs R9: MFMA dependency depth 4 -> 1 (four independent
// accumulators per output tile, tree-added) to cut dependent-MFMA latency.

__global__ __launch_bounds__(256, 1)
void rnn_kernel(const float* __restrict__ x,
                const float* __restrict__ W_ih,
                const float* __restrict__ b_ih,
                const float* __restrict__ W_hh,
                const float* __restrict__ b_hh,
                float* __restrict__ out)
{
    __shared__ __align__(16) char lds[8192];
    const int tid  = threadIdx.x;
    const int wv   = tid >> 6;        // 0..3 — one wave per SIMD, uniform code
    const int lane = tid & 63;
    const int col  = lane & 15;
    const int kg   = lane >> 4;
    const int bb0  = blockIdx.x * BT;

    // zero B exchange (h_0 = 0)
    for (int i = tid; i < 2048; i += 256) ((int*)lds)[i] = 0;

    const int OWN = wv;               // runtime-uniform; addresses only
    char* lbx = lds + (lane << 4);
    char*       wp  = lbx + (OWN << 10);
    const char* rp1 = lbx + ((((OWN + 1) & 3)) << 10);
    const char* rp2 = lbx + ((((OWN + 2) & 3)) << 10);
    const char* rp3 = lbx + ((((OWN + 3) & 3)) << 10);

    // ---- persistent weights for tt0 = 2*OWN, tt1 = 2*OWN+1
    bf16x8 whh0[4], whh1[4];
    const int tt0 = 2 * OWN, tt1 = tt0 + 1;
    #pragma unroll
    for (int q = 0; q < 4; ++q) {
        const int kkq = (OWN + q) & 3;                 // runtime-uniform addr
        {
            const float* pw = W_hh + (16 * tt0 + col) * NHID + 32 * kkq + 4 * kg;
            whh0[q] = pack8(*(const f32x4*)(pw), *(const f32x4*)(pw + 16));
        }
        {
            const float* pw = W_hh + (16 * tt1 + col) * NHID + 32 * kkq + 4 * kg;
            whh1[q] = pack8(*(const f32x4*)(pw), *(const f32x4*)(pw + 16));
        }
    }
    bf16x8 wihA0, wihB0, wihA1, wihB1;   // natural k (x side unpermuted)
    {
        const float* q0 = W_ih + (16 * tt0 + col) * NIN + 8 * kg;
        const float* q1 = W_ih + (16 * tt1 + col) * NIN + 8 * kg;
        wihA0 = pack8(*(const f32x4*)(q0),      *(const f32x4*)(q0 + 4));
        wihB0 = pack8(*(const f32x4*)(q0 + 32), *(const f32x4*)(q0 + 36));
        wihA1 = pack8(*(const f32x4*)(q1),      *(const f32x4*)(q1 + 4));
        wihB1 = pack8(*(const f32x4*)(q1 + 32), *(const f32x4*)(q1 + 36));
    }
    f32x4 bias0, bias1;
    {
        f32x4 bi = *(const f32x4*)(b_ih + 16 * tt0 + 4 * kg);
        f32x4 bh = *(const f32x4*)(b_hh + 16 * tt0 + 4 * kg);
        bias0 = bi + bh;
        bi = *(const f32x4*)(b_ih + 16 * tt1 + 4 * kg);
        bh = *(const f32x4*)(b_hh + 16 * tt1 + 4 * kg);
        bias1 = bi + bh;
    }

    const float* xlane = x + ((size_t)bb0 + col) * NIN + kg * 8;

    auto loadStage = [&](f32x4& v0, f32x4& v1, f32x4& v2, f32x4& v3, int t) {
        if (t < S_LEN) {
            const float* p = xlane + (size_t)t * (BATCH * NIN);
            v0 = *(const f32x4*)(p);      v1 = *(const f32x4*)(p + 4);
            v2 = *(const f32x4*)(p + 32); v3 = *(const f32x4*)(p + 36);
        }
    };
    auto computeXP = [&](const f32x4& v0, const f32x4& v1,
                         const f32x4& v2, const f32x4& v3,
                         f32x4& o0, f32x4& o1) {
        union { bf16x8 v; unsigned u[4]; } xa, xb;
        xa.u[0] = cvt_pk(v0[0], v0[1]); xa.u[1] = cvt_pk(v0[2], v0[3]);
        xa.u[2] = cvt_pk(v1[0], v1[1]); xa.u[3] = cvt_pk(v1[2], v1[3]);
        xb.u[0] = cvt_pk(v2[0], v2[1]); xb.u[1] = cvt_pk(v2[2], v2[3]);
        xb.u[2] = cvt_pk(v3[0], v3[1]); xb.u[3] = cvt_pk(v3[2], v3[3]);
        f32x4 p0 = bias0, p1 = bias1;
        p0 = MFMA(wihA0, xa.v, p0, 0, 0, 0);
        p1 = MFMA(wihA1, xa.v, p1, 0, 0, 0);
        p0 = MFMA(wihB0, xb.v, p0, 0, 0, 0);
        p1 = MFMA(wihB1, xb.v, p1, 0, 0, 0);
        o0 = p0; o1 = p1;
    };

    // ---- prologue: stages <- x(0..3); xp(0); refill stage0 <- x(4)
    f32x4 S00, S01, S02, S03, S10, S11, S12, S13;
    f32x4 S20, S21, S22, S23, S30, S31, S32, S33;
    loadStage(S00, S01, S02, S03, 0);
    loadStage(S10, S11, S12, S13, 1);
    loadStage(S20, S21, S22, S23, 2);
    loadStage(S30, S31, S32, S33, 3);
    f32x4 xc0, xc1, xn0, xn1;
    computeXP(S00, S01, S02, S03, xc0, xc1);
    loadStage(S00, S01, S02, S03, 4);
    bf16x8 Bo = {0, 0, 0, 0, 0, 0, 0, 0};       // own slice of h(0) = 0
    __syncthreads();                            // B-zeros visible

    auto cstep = [&](int t, f32x4& s0, f32x4& s1, f32x4& s2, f32x4& s3,
                     const f32x4& c0, const f32x4& c1,
                     f32x4& n0, f32x4& n1, bool last) {
        // partner B reads issue first; latency covered by own-MFMA + xp block
        const int rb = (t & 1) << 12;
        bf16x8 P1 = *(const bf16x8*)(rp1 + rb);
        bf16x8 P2 = *(const bf16x8*)(rp2 + rb);
        bf16x8 P3 = *(const bf16x8*)(rp3 + rb);

        const f32x4 z4 = {0.f, 0.f, 0.f, 0.f};
        // own-slot MFMAs: no LDS dependency, seeded with xp
        f32x4 aO0 = MFMA(whh0[0], Bo, c0, 0, 0, 0);
        f32x4 aO1 = MFMA(whh1[0], Bo, c1, 0, 0, 0);

        computeXP(s0, s1, s2, s3, n0, n1);       // xp(t+1): independent issue
        loadStage(s0, s1, s2, s3, t + 5);        // refill (consumed at t+4)

        // partner MFMAs: six INDEPENDENT accumulators (dep depth = 1)
        f32x4 aP10 = MFMA(whh0[1], P1, z4, 0, 0, 0);
        f32x4 aP11 = MFMA(whh1[1], P1, z4, 0, 0, 0);
        f32x4 aP20 = MFMA(whh0[2], P2, z4, 0, 0, 0);
        f32x4 aP21 = MFMA(whh1[2], P2, z4, 0, 0, 0);
        f32x4 aP30 = MFMA(whh0[3], P3, z4, 0, 0, 0);
        f32x4 aP31 = MFMA(whh1[3], P3, z4, 0, 0, 0);

        // tree-combine (2 vadd levels instead of 3 MFMA dependency hops)
        f32x4 pre0 = (aO0 + aP10) + (aP20 + aP30);
        f32x4 pre1 = (aO1 + aP11) + (aP21 + aP31);

        f32x4 a0, a1;
        #pragma unroll
        for (int i = 0; i < 4; ++i) a0[i] = tanh_fast(pre0[i]);
        #pragma unroll
        for (int i = 0; i < 4; ++i) a1[i] = tanh_fast(pre1[i]);

        if (last) {
            float* ob = out + ((size_t)bb0 + col) * NHID + 32 * OWN + 4 * kg;
            *(f32x4*)(ob)      = a0;
            *(f32x4*)(ob + 16) = a1;
            lds_barrier();
            return;
        }
        union { bf16x8 v; unsigned u[4]; } fb;
        fb.u[0] = cvt_pk(a0[0], a0[1]); fb.u[1] = cvt_pk(a0[2], a0[3]);
        fb.u[2] = cvt_pk(a1[0], a1[1]); fb.u[3] = cvt_pk(a1[2], a1[3]);
        Bo = fb.v;
        *(bf16x8*)(wp + (((t + 1) & 1) << 12)) = Bo;   // ds_write_b128
        lds_barrier();
    };

    for (int m = 0; m < 255; ++m) {
        const int t = 4 * m;
        cstep(t + 0, S10, S11, S12, S13, xc0, xc1, xn0, xn1, false);
        cstep(t + 1, S20, S21, S22, S23, xn0, xn1, xc0, xc1, false);
        cstep(t + 2, S30, S31, S32, S33, xc0, xc1, xn0, xn1, false);
        cstep(t + 3, S00, S01, S02, S03, xn0, xn1, xc0, xc1, false);
    }
    cstep(1020, S10, S11, S12, S13, xc0, xc1, xn0, xn1, false);
    cstep(1021, S20, S21, S22, S23, xn0, xn1, xc0, xc1, false);
    cstep(1022, S30, S31, S32, S33, xc0, xc1, xn0, xn1, false);
    cstep(1023, S00, S01, S02, S03, xn0, xn1, xc0, xc1, true);
}

extern "C" void kernel_launch(void* const* d_in, const int* in_sizes, int n_in,
                              void* d_out, int out_size, void* d_ws, size_t ws_size,
                              hipStream_t stream) {
    const float* x    = (const float*)d_in[0];
    const float* W_ih = (const float*)d_in[1];
    const float* b_ih = (const float*)d_in[2];
    const float* W_hh = (const float*)d_in[3];
    const float* b_hh = (const float*)d_in[4];
    float* out = (float*)d_out;

    dim3 grid(BATCH / BT);
    dim3 block(256);
    rnn_kernel<<<grid, block, 0, stream>>>(x, W_ih, b_ih, W_hh, b_hh, out);
}

// Round 15
// 456.335 us; speedup vs baseline: 1.9680x; 1.0028x over previous
//
#include <hip/hip_runtime.h>

#define S_LEN 1024
#define BATCH 4096
#define NIN 64
#define NHID 128
#define BT 16      // batch rows per block (one h-chain per block)

typedef __attribute__((ext_vector_type(8))) short bf16x8;
typedef __attribute__((ext_vector_type(4))) float f32x4;

__device__ __forceinline__ unsigned cvt_pk(float lo, float hi) {
    unsigned r;
    asm("v_cvt_pk_bf16_f32 %0, %1, %2" : "=v"(r) : "v"(lo), "v"(hi));
    return r;
}
__device__ __forceinline__ float tanh_fast(float z) {
    float u = __builtin_amdgcn_exp2f(z * 2.885390081777927f);
    return (u - 1.0f) * __builtin_amdgcn_rcpf(u + 1.0f);
}
// barrier without vmcnt drain (x prefetch loads stay in flight)
__device__ __forceinline__ void lds_barrier() {
    asm volatile("s_waitcnt lgkmcnt(0)\n\ts_barrier" ::: "memory");
    __builtin_amdgcn_sched_barrier(0);
}

#define MFMA __builtin_amdgcn_mfma_f32_16x16x32_bf16

__device__ __forceinline__ bf16x8 pack8(const f32x4& a, const f32x4& b) {
    union { bf16x8 v; unsigned u[4]; } r;
    r.u[0] = cvt_pk(a[0], a[1]); r.u[1] = cvt_pk(a[2], a[3]);
    r.u[2] = cvt_pk(b[0], b[1]); r.u[3] = cvt_pk(b[2], b[3]);
    return r.v;
}

// Permuted-k (verified R6-R9): B-slot (kk,kg,j) carries logical hidden index
// m = 32kk + 16*(j>>2) + 4kg + (j&3). Wave OWN (=wv) owns tt {2*OWN, 2*OWN+1}:
// its accs pack same-lane into B-slot OWN; own slot stays in registers, 3
// partner slots cross LDS. LDS: 2 bufs x 4KB (buf b<<12, slot kk<<10, lane<<4).
// R15 vs R9: the own-slot MFMA for step t+1 is issued BETWEEN the ds_write and
// the barrier (it needs no LDS), so the write-drain window does useful work and
// the own contribution leaves the critical chain. Loop carries aO, not xp.

__global__ __launch_bounds__(256, 1)
void rnn_kernel(const float* __restrict__ x,
                const float* __restrict__ W_ih,
                const float* __restrict__ b_ih,
                const float* __restrict__ W_hh,
                const float* __restrict__ b_hh,
                float* __restrict__ out)
{
    __shared__ __align__(16) char lds[8192];
    const int tid  = threadIdx.x;
    const int wv   = tid >> 6;        // 0..3 — one wave per SIMD, uniform code
    const int lane = tid & 63;
    const int col  = lane & 15;
    const int kg   = lane >> 4;
    const int bb0  = blockIdx.x * BT;

    // zero B exchange (h_0 = 0)
    for (int i = tid; i < 2048; i += 256) ((int*)lds)[i] = 0;

    const int OWN = wv;               // runtime-uniform; addresses only
    char* lbx = lds + (lane << 4);
    char*       wp  = lbx + (OWN << 10);
    const char* rp1 = lbx + ((((OWN + 1) & 3)) << 10);
    const char* rp2 = lbx + ((((OWN + 2) & 3)) << 10);
    const char* rp3 = lbx + ((((OWN + 3) & 3)) << 10);

    // ---- persistent weights for tt0 = 2*OWN, tt1 = 2*OWN+1
    bf16x8 whh0[4], whh1[4];
    const int tt0 = 2 * OWN, tt1 = tt0 + 1;
    #pragma unroll
    for (int q = 0; q < 4; ++q) {
        const int kkq = (OWN + q) & 3;                 // runtime-uniform addr
        {
            const float* pw = W_hh + (16 * tt0 + col) * NHID + 32 * kkq + 4 * kg;
            whh0[q] = pack8(*(const f32x4*)(pw), *(const f32x4*)(pw + 16));
        }
        {
            const float* pw = W_hh + (16 * tt1 + col) * NHID + 32 * kkq + 4 * kg;
            whh1[q] = pack8(*(const f32x4*)(pw), *(const f32x4*)(pw + 16));
        }
    }
    bf16x8 wihA0, wihB0, wihA1, wihB1;   // natural k (x side unpermuted)
    {
        const float* q0 = W_ih + (16 * tt0 + col) * NIN + 8 * kg;
        const float* q1 = W_ih + (16 * tt1 + col) * NIN + 8 * kg;
        wihA0 = pack8(*(const f32x4*)(q0),      *(const f32x4*)(q0 + 4));
        wihB0 = pack8(*(const f32x4*)(q0 + 32), *(const f32x4*)(q0 + 36));
        wihA1 = pack8(*(const f32x4*)(q1),      *(const f32x4*)(q1 + 4));
        wihB1 = pack8(*(const f32x4*)(q1 + 32), *(const f32x4*)(q1 + 36));
    }
    f32x4 bias0, bias1;
    {
        f32x4 bi = *(const f32x4*)(b_ih + 16 * tt0 + 4 * kg);
        f32x4 bh = *(const f32x4*)(b_hh + 16 * tt0 + 4 * kg);
        bias0 = bi + bh;
        bi = *(const f32x4*)(b_ih + 16 * tt1 + 4 * kg);
        bh = *(const f32x4*)(b_hh + 16 * tt1 + 4 * kg);
        bias1 = bi + bh;
    }

    const float* xlane = x + ((size_t)bb0 + col) * NIN + kg * 8;

    auto loadStage = [&](f32x4& v0, f32x4& v1, f32x4& v2, f32x4& v3, int t) {
        if (t < S_LEN) {
            const float* p = xlane + (size_t)t * (BATCH * NIN);
            v0 = *(const f32x4*)(p);      v1 = *(const f32x4*)(p + 4);
            v2 = *(const f32x4*)(p + 32); v3 = *(const f32x4*)(p + 36);
        }
    };
    auto computeXP = [&](const f32x4& v0, const f32x4& v1,
                         const f32x4& v2, const f32x4& v3,
                         f32x4& o0, f32x4& o1) {
        union { bf16x8 v; unsigned u[4]; } xa, xb;
        xa.u[0] = cvt_pk(v0[0], v0[1]); xa.u[1] = cvt_pk(v0[2], v0[3]);
        xa.u[2] = cvt_pk(v1[0], v1[1]); xa.u[3] = cvt_pk(v1[2], v1[3]);
        xb.u[0] = cvt_pk(v2[0], v2[1]); xb.u[1] = cvt_pk(v2[2], v2[3]);
        xb.u[2] = cvt_pk(v3[0], v3[1]); xb.u[3] = cvt_pk(v3[2], v3[3]);
        f32x4 p0 = bias0, p1 = bias1;
        p0 = MFMA(wihA0, xa.v, p0, 0, 0, 0);
        p1 = MFMA(wihA1, xa.v, p1, 0, 0, 0);
        p0 = MFMA(wihB0, xb.v, p0, 0, 0, 0);
        p1 = MFMA(wihB1, xb.v, p1, 0, 0, 0);
        o0 = p0; o1 = p1;
    };

    // ---- prologue: stages <- x(0..3); aO(0) = xp(0) (Bo(0)=0); refill S0 <- x(4)
    f32x4 S00, S01, S02, S03, S10, S11, S12, S13;
    f32x4 S20, S21, S22, S23, S30, S31, S32, S33;
    loadStage(S00, S01, S02, S03, 0);
    loadStage(S10, S11, S12, S13, 1);
    loadStage(S20, S21, S22, S23, 2);
    loadStage(S30, S31, S32, S33, 3);
    f32x4 aO0, aO1;                   // own-slot contribution incl. xp (carried)
    computeXP(S00, S01, S02, S03, aO0, aO1);   // Bo(0)=0 -> aO(0) = xp(0)
    loadStage(S00, S01, S02, S03, 4);
    bf16x8 Bo = {0, 0, 0, 0, 0, 0, 0, 0};      // own slice of h(0) = 0
    __syncthreads();                           // B-zeros visible

    auto cstep = [&](int t, f32x4& s0, f32x4& s1, f32x4& s2, f32x4& s3,
                     bool last) {
        // partner B reads issue first; latency covered by the xp block below
        const int rb = (t & 1) << 12;
        bf16x8 P1 = *(const bf16x8*)(rp1 + rb);
        bf16x8 P2 = *(const bf16x8*)(rp2 + rb);
        bf16x8 P3 = *(const bf16x8*)(rp3 + rb);

        // xp(t+1): independent issue, covers the partner-read latency
        f32x4 xn0, xn1;
        computeXP(s0, s1, s2, s3, xn0, xn1);

        // partner MFMAs chained onto the carried own contribution aO
        f32x4 a0 = aO0, a1 = aO1;
        a0 = MFMA(whh0[1], P1, a0, 0, 0, 0);
        a1 = MFMA(whh1[1], P1, a1, 0, 0, 0);
        a0 = MFMA(whh0[2], P2, a0, 0, 0, 0);
        a1 = MFMA(whh1[2], P2, a1, 0, 0, 0);
        a0 = MFMA(whh0[3], P3, a0, 0, 0, 0);
        a1 = MFMA(whh1[3], P3, a1, 0, 0, 0);

        #pragma unroll
        for (int i = 0; i < 4; ++i) a0[i] = tanh_fast(a0[i]);
        #pragma unroll
        for (int i = 0; i < 4; ++i) a1[i] = tanh_fast(a1[i]);

        if (last) {
            float* ob = out + ((size_t)bb0 + col) * NHID + 32 * OWN + 4 * kg;
            *(f32x4*)(ob)      = a0;
            *(f32x4*)(ob + 16) = a1;
            lds_barrier();
            return;
        }
        // pack h(t+1) own slice, write to the (t+1)-parity buffer
        union { bf16x8 v; unsigned u[4]; } fb;
        fb.u[0] = cvt_pk(a0[0], a0[1]); fb.u[1] = cvt_pk(a0[2], a0[3]);
        fb.u[2] = cvt_pk(a1[0], a1[1]); fb.u[3] = cvt_pk(a1[2], a1[3]);
        Bo = fb.v;
        *(bf16x8*)(wp + (((t + 1) & 1) << 12)) = Bo;   // ds_write_b128

        // write-drain window: own-slot MFMA for t+1 (no LDS) + stage refill
        aO0 = MFMA(whh0[0], Bo, xn0, 0, 0, 0);
        aO1 = MFMA(whh1[0], Bo, xn1, 0, 0, 0);
        loadStage(s0, s1, s2, s3, t + 5);              // refill (consumed t+4)

        lds_barrier();
    };

    for (int m = 0; m < 255; ++m) {
        const int t = 4 * m;
        cstep(t + 0, S10, S11, S12, S13, false);
        cstep(t + 1, S20, S21, S22, S23, false);
        cstep(t + 2, S30, S31, S32, S33, false);
        cstep(t + 3, S00, S01, S02, S03, false);
    }
    cstep(1020, S10, S11, S12, S13, false);
    cstep(1021, S20, S21, S22, S23, false);
    cstep(1022, S30, S31, S32, S33, false);
    cstep(1023, S00, S01, S02, S03, true);
}

extern "C" void kernel_launch(void* const* d_in, const int* in_sizes, int n_in,
                              void* d_out, int out_size, void* d_ws, size_t ws_size,
                              hipStream_t stream) {
    const float* x    = (const float*)d_in[0];
    const float* W_ih = (const float*)d_in[1];
    const float* b_ih = (const float*)d_in[2];
    const float* W_hh = (const float*)d_in[3];
    const float* b_hh = (const float*)d_in[4];
    float* out = (float*)d_out;

    dim3 grid(BATCH / BT);
    dim3 block(256);
    rnn_kernel<<<grid, block, 0, stream>>>(x, W_ih, b_ih, W_hh, b_hh, out);
}